// Round 1
// baseline (62.710 us; speedup 1.0000x reference)
//
#include <hip/hip_runtime.h>
#include <hip/hip_bf16.h>

namespace {
constexpr int kB = 2, kW = 5, kS = 5, kQ = 75, kC = 64, kHW = 441;
constexpr int kNP = 448;   // support positions padded (14 * 32)
constexpr int kMP = 512;   // query positions padded (4 waves * 128 cols)
constexpr int kNT = kNP / 32;

typedef short bf16x8 __attribute__((ext_vector_type(8)));
typedef float f32x16 __attribute__((ext_vector_type(16)));
}

// ---- prep: shot-mean + L2 normalize over c, write bf16 position-major ----
__global__ __launch_bounds__(256) void prep_support_k(const float* __restrict__ sup,
                                                      unsigned short* __restrict__ snT) {
  int gw = (blockIdx.x * 256 + threadIdx.x) >> 6;  // one wave per (b,w,n)
  int lane = threadIdx.x & 63;                     // lane = channel
  if (gw >= kB * kW * kNP) return;
  int n = gw % kNP;
  int bw = gw / kNP;  // b*kW + w
  float v = 0.f;
  if (n < kHW) {
    const float* p = sup + ((size_t)(bw * kS) * kC + lane) * kHW + n;
    float s = 0.f;
#pragma unroll
    for (int k = 0; k < kS; ++k) s += p[(size_t)k * kC * kHW];
    v = s * (1.f / kS);
  }
  float ss = v * v;
#pragma unroll
  for (int off = 1; off < 64; off <<= 1) ss += __shfl_xor(ss, off, 64);
  float d = fmaxf(sqrtf(ss), 1e-12f);
  __hip_bfloat16 o = __float2bfloat16(v / d);
  snT[(size_t)gw * kC + lane] = *reinterpret_cast<unsigned short*>(&o);
}

__global__ __launch_bounds__(256) void prep_query_k(const float* __restrict__ qry,
                                                    unsigned short* __restrict__ qnT) {
  int gw = (blockIdx.x * 256 + threadIdx.x) >> 6;  // one wave per (b,q,m)
  int lane = threadIdx.x & 63;
  if (gw >= kB * kQ * kMP) return;
  int n = gw % kMP;
  int bq = gw / kMP;
  float v = 0.f;
  if (n < kHW) v = qry[((size_t)bq * kC + lane) * kHW + n];
  float ss = v * v;
#pragma unroll
  for (int off = 1; off < 64; off <<= 1) ss += __shfl_xor(ss, off, 64);
  float d = fmaxf(sqrtf(ss), 1e-12f);
  __hip_bfloat16 o = __float2bfloat16(v / d);
  qnT[(size_t)gw * kC + lane] = *reinterpret_cast<unsigned short*>(&o);
}

// ---- main: per (b,q,w): sim = Sn(441x64) x Qn^T(64x441), max over rows(n), sum cols(m) ----
__device__ __forceinline__ float max16(const f32x16& a) {
  float t0 = fmaxf(fmaxf(a[0], a[1]), fmaxf(a[2], a[3]));
  float t1 = fmaxf(fmaxf(a[4], a[5]), fmaxf(a[6], a[7]));
  float t2 = fmaxf(fmaxf(a[8], a[9]), fmaxf(a[10], a[11]));
  float t3 = fmaxf(fmaxf(a[12], a[13]), fmaxf(a[14], a[15]));
  return fmaxf(fmaxf(t0, t1), fmaxf(t2, t3));
}
__device__ __forceinline__ float max12(const f32x16& a) {
  float t0 = fmaxf(fmaxf(a[0], a[1]), fmaxf(a[2], a[3]));
  float t1 = fmaxf(fmaxf(a[4], a[5]), fmaxf(a[6], a[7]));
  float t2 = fmaxf(fmaxf(a[8], a[9]), fmaxf(a[10], a[11]));
  return fmaxf(fmaxf(t0, t1), t2);
}

__global__ __launch_bounds__(256) void dn4_main_k(const unsigned short* __restrict__ qnT,
                                                  const unsigned short* __restrict__ snT,
                                                  float* __restrict__ out) {
  __shared__ unsigned short As[kNP * kC];  // 57344 B, XOR-swizzled support tile
  const int idx = blockIdx.x;  // = (b*kQ+q)*kW + w  == output index
  const int w = idx % kW;
  const int bq = idx / kW;
  const int b = bq / kQ;
  const int tid = threadIdx.x;

  // stage support tile, swizzle 16B chunks: chunk(n,k16) -> n*8 + (k16 ^ (n&7))
  const uint4* src = reinterpret_cast<const uint4*>(snT + (size_t)(b * kW + w) * kNP * kC);
  uint4* dst = reinterpret_cast<uint4*>(As);
#pragma unroll
  for (int it = 0; it < (kNP * kC / 8) / 256; ++it) {  // 14 iters
    int i = it * 256 + tid;
    int n = i >> 3, k16 = i & 7;
    dst[n * 8 + (k16 ^ (n & 7))] = src[i];
  }

  const int lane = tid & 63;
  const int half = lane >> 5;
  const int lm = lane & 31;
  const int wid = tid >> 6;  // 0..3, each wave owns 128 query cols

  // B fragments (query) in registers: 4 col-tiles x 4 K-steps
  bf16x8 bf[4][4];
  const unsigned short* qb = qnT + (size_t)bq * kMP * kC;
#pragma unroll
  for (int ct = 0; ct < 4; ++ct) {
    int m = wid * 128 + ct * 32 + lm;
#pragma unroll
    for (int kk = 0; kk < 4; ++kk)
      bf[ct][kk] = *reinterpret_cast<const bf16x8*>(qb + (size_t)m * kC + kk * 16 + half * 8);
  }
  __syncthreads();

  f32x16 z;
#pragma unroll
  for (int r = 0; r < 16; ++r) z[r] = 0.f;
  float rm[4] = {-INFINITY, -INFINITY, -INFINITY, -INFINITY};

  for (int nt = 0; nt < kNT; ++nt) {
    bf16x8 af[4];
    int n = nt * 32 + lm;
#pragma unroll
    for (int kk = 0; kk < 4; ++kk) {
      int k16 = kk * 2 + half;
      af[kk] = *reinterpret_cast<const bf16x8*>(As + ((size_t)(n * 8 + (k16 ^ (n & 7))) << 3));
    }
    if (nt < kNT - 1) {
#pragma unroll
      for (int ct = 0; ct < 4; ++ct) {
        f32x16 acc = z;
#pragma unroll
        for (int kk = 0; kk < 4; ++kk)
          acc = __builtin_amdgcn_mfma_f32_32x32x16_bf16(af[kk], bf[ct][kk], acc, 0, 0, 0);
        rm[ct] = fmaxf(rm[ct], max16(acc));
      }
    } else {
      // tail tile: rows n=432..447; valid n<441 -> local row < 25.
      // row = (r&3)+8*(r>>2)+4*half: half0 invalid regs {13,14,15}, half1 invalid {12..15}
#pragma unroll
      for (int ct = 0; ct < 4; ++ct) {
        f32x16 acc = z;
#pragma unroll
        for (int kk = 0; kk < 4; ++kk)
          acc = __builtin_amdgcn_mfma_f32_32x32x16_bf16(af[kk], bf[ct][kk], acc, 0, 0, 0);
        float t = max12(acc);
        if (half == 0) t = fmaxf(t, acc[12]);  // row 24, still valid
        rm[ct] = fmaxf(rm[ct], t);
      }
    }
  }

  // combine the complementary row-halves, then sum the wave's 128 cols
  float s = 0.f;
#pragma unroll
  for (int ct = 0; ct < 4; ++ct) s += fmaxf(rm[ct], __shfl_xor(rm[ct], 32, 64));
#pragma unroll
  for (int off = 1; off < 32; off <<= 1) s += __shfl_xor(s, off, 64);

  __shared__ float part[4];
  if (lane == 0) part[wid] = s;
  __syncthreads();
  if (tid == 0) out[idx] = part[0] + part[1] + part[2] + part[3];
}

extern "C" void kernel_launch(void* const* d_in, const int* in_sizes, int n_in,
                              void* d_out, int out_size, void* d_ws, size_t ws_size,
                              hipStream_t stream) {
  const float* sup = (const float*)d_in[0];
  const float* qry = (const float*)d_in[2];
  float* out = (float*)d_out;

  unsigned short* snT = (unsigned short*)d_ws;                       // 573,440 B
  unsigned short* qnT = snT + (size_t)kB * kW * kNP * kC;            // 9,830,400 B

  int sw = kB * kW * kNP;  // 4480 waves
  prep_support_k<<<(sw * 64) / 256, 256, 0, stream>>>(sup, snT);
  int qw = kB * kQ * kMP;  // 76800 waves
  prep_query_k<<<(qw * 64) / 256, 256, 0, stream>>>(qry, qnT);
  dn4_main_k<<<kB * kQ * kW, 256, 0, stream>>>(qnT, snT, out);
}

// Round 2
// 44.519 us; speedup vs baseline: 1.4086x; 1.4086x over previous
//
#include <hip/hip_runtime.h>
#include <hip/hip_bf16.h>

namespace {
constexpr int kB = 2, kW = 5, kS = 5, kQ = 75, kC = 64, kHW = 441;
constexpr int kNP = 448;   // support positions padded (14 * 32)
constexpr int kMP = 448;   // query positions padded (14 col-tiles)
constexpr int kNT = kNP / 32;     // 14 row tiles
constexpr int kCHUNK = 112;       // positions per prep block (4 chunks/image)
constexpr int kLDT = 65;          // LDS stride for img_t (odd -> conflict-free)

typedef short bf16x8 __attribute__((ext_vector_type(8)));
typedef float f32x16 __attribute__((ext_vector_type(16)));
}

// ---- fused prep: shot-mean (support) + L2 normalize + transpose to bf16 ----
// grid: 40 support chunk-blocks (10 images x 4 chunks) + 600 query chunk-blocks
__global__ __launch_bounds__(256) void prep_k(const float* __restrict__ sup,
                                              const float* __restrict__ qry,
                                              unsigned short* __restrict__ snT,
                                              unsigned short* __restrict__ qnT) {
  __shared__ float img_t[kCHUNK * kLDT];  // [m][c] transposed, 29120 B
  __shared__ float inv[kCHUNK];
  const int tid = threadIdx.x;
  const int blk = blockIdx.x;

  int m0, mcnt;
  unsigned short* dst;
  const bool is_sup = blk < kB * kW * 4;

  if (is_sup) {
    int bw = blk >> 2, chunk = blk & 3;
    m0 = chunk * kCHUNK;
    mcnt = min(kCHUNK, kHW - m0);
    const float* base = sup + (size_t)bw * kS * kC * kHW;
    for (int i = tid; i < kC * kCHUNK; i += 256) {
      int c = i / kCHUNK, mm = i % kCHUNK;
      float v = 0.f;
      if (mm < mcnt) {
        const float* p = base + (size_t)c * kHW + m0 + mm;
        float s = 0.f;
#pragma unroll
        for (int k = 0; k < kS; ++k) s += p[(size_t)k * kC * kHW];
        v = s * (1.f / kS);
      }
      img_t[mm * kLDT + c] = v;
    }
    dst = snT + (size_t)bw * kNP * kC;
  } else {
    int qb = blk - kB * kW * 4;
    int bq = qb >> 2, chunk = qb & 3;
    m0 = chunk * kCHUNK;
    mcnt = min(kCHUNK, kHW - m0);
    const float* base = qry + (size_t)bq * kC * kHW;
    for (int i = tid; i < kC * kCHUNK; i += 256) {
      int c = i / kCHUNK, mm = i % kCHUNK;
      img_t[mm * kLDT + c] = (mm < mcnt) ? base[(size_t)c * kHW + m0 + mm] : 0.f;
    }
    dst = qnT + (size_t)bq * kMP * kC;
  }
  __syncthreads();

  if (tid < kCHUNK) {
    float ss = 0.f;
#pragma unroll
    for (int c = 0; c < kC; ++c) { float v = img_t[tid * kLDT + c]; ss += v * v; }
    inv[tid] = 1.f / fmaxf(sqrtf(ss), 1e-12f);
  }
  __syncthreads();

  // write bf16 position-major, 8 channels (16B) per thread per iter
  for (int i8 = tid; i8 < kCHUNK * 8; i8 += 256) {  // 3.5 iters
    int m = i8 >> 3, c8 = (i8 & 7) * 8;
    float sc = inv[m];
    union { unsigned short u[8]; uint4 v; } pk;
#pragma unroll
    for (int j = 0; j < 8; ++j) {
      __hip_bfloat16 o = __float2bfloat16(img_t[m * kLDT + c8 + j] * sc);
      pk.u[j] = *reinterpret_cast<unsigned short*>(&o);
    }
    *reinterpret_cast<uint4*>(dst + ((size_t)(m0 + m) * kC + c8)) = pk.v;
  }
}

// ---- main: per (b,q,w): sim = Sn(448x64) x Qn^T(64x448), max over rows(n), sum cols(m) ----
__device__ __forceinline__ float max16_v(const f32x16& a) {
  float m0 = fmaxf(fmaxf(a[0], a[1]), a[2]);
  float m1 = fmaxf(fmaxf(a[3], a[4]), a[5]);
  float m2 = fmaxf(fmaxf(a[6], a[7]), a[8]);
  float m3 = fmaxf(fmaxf(a[9], a[10]), a[11]);
  float m4 = fmaxf(fmaxf(a[12], a[13]), a[14]);
  float t0 = fmaxf(fmaxf(m0, m1), m2);
  float t1 = fmaxf(fmaxf(m3, m4), a[15]);
  return fmaxf(t0, t1);
}
__device__ __forceinline__ float max12_v(const f32x16& a) {
  float m0 = fmaxf(fmaxf(a[0], a[1]), a[2]);
  float m1 = fmaxf(fmaxf(a[3], a[4]), a[5]);
  float m2 = fmaxf(fmaxf(a[6], a[7]), a[8]);
  float m3 = fmaxf(fmaxf(a[9], a[10]), a[11]);
  return fmaxf(fmaxf(m0, m1), fmaxf(m2, m3));
}

__global__ __launch_bounds__(256) void dn4_main_k(const unsigned short* __restrict__ qnT,
                                                  const unsigned short* __restrict__ snT,
                                                  float* __restrict__ out) {
  __shared__ unsigned short As[kNP * kC];  // 57344 B, XOR-swizzled support tile
  const int idx = blockIdx.x;  // = (b*kQ+q)*kW + w
  const int w = idx % kW;
  const int bq = idx / kW;
  const int b = bq / kQ;
  const int tid = threadIdx.x;

  // stage support tile; swizzle 16B chunks: chunk(n,k16) -> n*8 + (k16 ^ (n&7))
  {
    const uint4* src = reinterpret_cast<const uint4*>(snT + (size_t)(b * kW + w) * kNP * kC);
    uint4* dst = reinterpret_cast<uint4*>(As);
#pragma unroll
    for (int it = 0; it < (kNP * kC / 8) / 256; ++it) {  // 14 iters
      int i = it * 256 + tid;
      int n = i >> 3, k16 = i & 7;
      dst[n * 8 + (k16 ^ (n & 7))] = src[i];
    }
  }

  const int lane = tid & 63;
  const int half = lane >> 5;
  const int lm = lane & 31;
  const int wid = tid >> 6;
  // col-tile distribution over 14 tiles: waves get {4,4,3,3}
  const int ct0 = (wid < 2) ? wid * 4 : 8 + (wid - 2) * 3;
  const int nct = (wid < 2) ? 4 : 3;

  // B fragments (query) in registers
  bf16x8 bf[4][4];
  const unsigned short* qb = qnT + (size_t)bq * kMP * kC;
#pragma unroll
  for (int ct = 0; ct < 4; ++ct) {
    if (ct < nct) {
      int m = (ct0 + ct) * 32 + lm;
#pragma unroll
      for (int kk = 0; kk < 4; ++kk)
        bf[ct][kk] = *reinterpret_cast<const bf16x8*>(qb + (size_t)m * kC + kk * 16 + half * 8);
    }
  }
  __syncthreads();

  f32x16 z;
#pragma unroll
  for (int r = 0; r < 16; ++r) z[r] = 0.f;
  float rm[4] = {-INFINITY, -INFINITY, -INFINITY, -INFINITY};

  for (int nt = 0; nt < kNT; ++nt) {
    bf16x8 af[4];
    int n = nt * 32 + lm;
#pragma unroll
    for (int kk = 0; kk < 4; ++kk) {
      int k16 = kk * 2 + half;
      af[kk] = *reinterpret_cast<const bf16x8*>(As + ((size_t)(n * 8 + (k16 ^ (n & 7))) << 3));
    }
    if (nt < kNT - 1) {
#pragma unroll
      for (int ct = 0; ct < 4; ++ct) {
        if (ct < nct) {
          f32x16 acc = z;
#pragma unroll
          for (int kk = 0; kk < 4; ++kk)
            acc = __builtin_amdgcn_mfma_f32_32x32x16_bf16(af[kk], bf[ct][kk], acc, 0, 0, 0);
          rm[ct] = fmaxf(rm[ct], max16_v(acc));
        }
      }
    } else {
      // tail tile rows n=416..447; valid n<441 -> local row <= 24.
      // row = (r&3)+8*(r>>2)+4*half: half0 invalid regs {13,14,15}, half1 invalid {12..15}
#pragma unroll
      for (int ct = 0; ct < 4; ++ct) {
        if (ct < nct) {
          f32x16 acc = z;
#pragma unroll
          for (int kk = 0; kk < 4; ++kk)
            acc = __builtin_amdgcn_mfma_f32_32x32x16_bf16(af[kk], bf[ct][kk], acc, 0, 0, 0);
          float t = max12_v(acc);
          if (half == 0) t = fmaxf(t, acc[12]);  // row 24 still valid
          rm[ct] = fmaxf(rm[ct], t);
        }
      }
    }
  }

  // combine complementary row-halves, then sum this wave's columns
  float s = 0.f;
#pragma unroll
  for (int ct = 0; ct < 4; ++ct) {
    if (ct < nct) s += fmaxf(rm[ct], __shfl_xor(rm[ct], 32, 64));
  }
#pragma unroll
  for (int off = 1; off < 32; off <<= 1) s += __shfl_xor(s, off, 64);

  __shared__ float part[4];
  if (lane == 0) part[wid] = s;
  __syncthreads();
  if (tid == 0) out[idx] = part[0] + part[1] + part[2] + part[3];
}

extern "C" void kernel_launch(void* const* d_in, const int* in_sizes, int n_in,
                              void* d_out, int out_size, void* d_ws, size_t ws_size,
                              hipStream_t stream) {
  const float* sup = (const float*)d_in[0];
  const float* qry = (const float*)d_in[2];
  float* out = (float*)d_out;

  unsigned short* snT = (unsigned short*)d_ws;                 // 10*448*64*2 = 573,440 B
  unsigned short* qnT = snT + (size_t)kB * kW * kNP * kC;      // 150*448*64*2 = 8,601,600 B

  int prep_blocks = kB * kW * 4 + kB * kQ * 4;  // 40 + 600 = 640
  prep_k<<<prep_blocks, 256, 0, stream>>>(sup, qry, snT, qnT);
  dn4_main_k<<<kB * kQ * kW, 256, 0, stream>>>(qnT, snT, out);
}